// Round 2
// baseline (273.754 us; speedup 1.0000x reference)
//
#include <hip/hip_runtime.h>
#include <cstdint>
#include <cstddef>

typedef int int32x4  __attribute__((ext_vector_type(4)));
typedef int int32x16 __attribute__((ext_vector_type(16)));

#define AS1 __attribute__((address_space(1)))
#define AS3 __attribute__((address_space(3)))

__device__ __forceinline__ void gload_lds16(const void* g, void* l) {
    __builtin_amdgcn_global_load_lds((const AS1 void*)g, (AS3 void*)l, 16, 0, 0);
}

#define MFMA_I8(a, b, c) __builtin_amdgcn_mfma_i32_32x32x32_i8((a), (b), (c), 0, 0, 0)

// ---------------------------------------------------------------------------
// Kernel 1: x (fp32, int8-valued) -> A8 (int8) + row sums rs. (frozen)
// ---------------------------------------------------------------------------
__global__ __launch_bounds__(256) void quant_x(const float* __restrict__ x,
                                               signed char* __restrict__ A8,
                                               int* __restrict__ rs) {
    const int row = blockIdx.x;
    const int t = threadIdx.x;
    const float4* xr = (const float4*)(x + (size_t)row * 4096);
    char4* ar = (char4*)(A8 + (size_t)row * 4096);
    int s = 0;
#pragma unroll
    for (int i = 0; i < 4; i++) {
        const int idx = i * 256 + t;
        float4 v = xr[idx];
        int a0 = (int)v.x, a1 = (int)v.y, a2 = (int)v.z, a3 = (int)v.w;
        s += a0 + a1 + a2 + a3;
        char4 c;
        c.x = (signed char)a0; c.y = (signed char)a1;
        c.z = (signed char)a2; c.w = (signed char)a3;
        ar[idx] = c;
    }
#pragma unroll
    for (int off = 32; off > 0; off >>= 1) s += __shfl_down(s, off);
    __shared__ int wsum[4];
    if ((t & 63) == 0) wsum[t >> 6] = s;
    __syncthreads();
    if (t == 0) rs[row] = wsum[0] + wsum[1] + wsum[2] + wsum[3];
}

// ---------------------------------------------------------------------------
// Kernel 2: y -> B8T (int8, N-major) + col sums sy. (frozen, round-1 version)
// ---------------------------------------------------------------------------
__global__ __launch_bounds__(256) void quant_y(const float* __restrict__ y,
                                               signed char* __restrict__ B8T,
                                               int* __restrict__ sy) {
    __shared__ int tile[64 * 17];   // [n][k/4], pitch 17 dwords
    __shared__ int ssum[64];
    const int nt = blockIdx.x * 64;
    const int kt = blockIdx.y * 64;
    const int t = threadIdx.x;
    if (t < 64) ssum[t] = 0;
    __syncthreads();

    const int n4 = (t & 15) * 4;
    const int kb = (t >> 4) * 4;
    int b[4][4];
#pragma unroll
    for (int i = 0; i < 4; i++) {
        float4 v = *(const float4*)(y + (size_t)(kt + kb + i) * 4096 + nt + n4);
        b[i][0] = (int)v.x - 128; b[i][1] = (int)v.y - 128;
        b[i][2] = (int)v.z - 128; b[i][3] = (int)v.w - 128;
    }
#pragma unroll
    for (int j = 0; j < 4; j++) {
        const int s = b[0][j] + b[1][j] + b[2][j] + b[3][j];
        const int w = (b[0][j] & 255) | ((b[1][j] & 255) << 8) |
                      ((b[2][j] & 255) << 16) | (b[3][j] << 24);
        tile[(n4 + j) * 17 + (kb >> 2)] = w;
        atomicAdd(&ssum[n4 + j], s);
    }
    __syncthreads();

    const int n = t >> 2;
    const int kq = (t & 3) * 4;
    int32x4 o;
    o.x = tile[n * 17 + kq + 0];
    o.y = tile[n * 17 + kq + 1];
    o.z = tile[n * 17 + kq + 2];
    o.w = tile[n * 17 + kq + 3];
    *(int32x4*)(B8T + (size_t)(nt + n) * 4096 + kt + kq * 4) = o;
    if (t < 64) atomicAdd(&sy[nt + t], ssum[t]);
}

// ---------------------------------------------------------------------------
// Kernel 3: int8 GEMM — OCCUPANCY round. Rounds 0-1 proved the schedule is
// not the limiter (1-barrier vs 8-barrier/tile = identical 88.5us, MfmaUtil
// 34%): waves are latency-bound with only 2 waves/SIMD to hide per-wave
// stalls (~2700 cyc non-MFMA per wave per tile vs 586 MFMA).
// NEW geometry: block tile 128x128, BK=64, 4 waves 2x2, wave tile 64x64 =
// 2x2 of 32x32x32 i8 MFMAs. acc = 64 AGPRs (was 128), LDS = 3 x 16KB = 48KB
// (was 72KB) -> 3 blocks/CU = 12 waves/CU = 3 waves/SIMD (was 2).
// Pipeline unchanged in spirit: 3-stage, raw s_barrier, counted vmcnt(4)
// (4 gload16/thread/tile; tile i+1's 4 stay in flight across the barrier).
// XCD swizzle: 1024 blocks, til=(lin&7)*128+(lin>>3) bijective; each XCD
// owns 4 consecutive M-rows (2MB A panel L2-resident).
// LDS layout: dense 64B rows, XOR chunk swizzle slot = chunk ^ ((row>>1)&3),
// applied on the GLOBAL source address (global_load_lds dest must be linear).
// Frags: A[m=lane&31][k=(lane>>5)*16+j]; C/D col=lane&31,
// row=(reg&3)+8*(reg>>2)+4*(lane>>5)  (verified, absmax 32).
// Epilogue: C = 7.5e-4 * (P - 32*rs[m] + 66*sy[n] - 8650752)
// ---------------------------------------------------------------------------
__global__ __launch_bounds__(256, 3) void gemm_i8(const signed char* __restrict__ A8,
                                                  const signed char* __restrict__ B8T,
                                                  const int* __restrict__ rs,
                                                  const int* __restrict__ sy,
                                                  float* __restrict__ C) {
    __shared__ __align__(16) signed char As[3 * 8192];   // 128 rows x 64B x 3
    __shared__ __align__(16) signed char Bs[3 * 8192];   // 128 rows x 64B x 3
    const int tid = threadIdx.x;
    const int lin = blockIdx.y * 32 + blockIdx.x;
    const int til = (lin & 7) * 128 + (lin >> 3);   // XCD-contiguous tiles
    const int bm = (til >> 5) * 128;
    const int bn = (til & 31) * 128;
    const int lane = tid & 63;
    const int wave = tid >> 6;
    const int wm = (wave >> 1) * 64;    // 2 m-waves x 64
    const int wn = (wave & 1) * 64;     // 2 n-waves x 64
    const int mr = lane & 31;
    const int kh = lane >> 5;

    int32x16 acc[2][2] = {};

    // staging: thread tid -> row (tid>>2) (+64*p), chunk (tid&3) XOR-swizzled
    // at the global source so LDS dest stays linear.
    const int srow = tid >> 2;
    const int scol = ((tid & 3) ^ ((tid >> 3) & 3)) * 16;
    const size_t arow = (size_t)(bm + srow) * 4096 + scol;
    const size_t brow = (size_t)(bn + srow) * 4096 + scol;

    // fragment LDS offsets: row = wtile + i*32 + mr; chunk = ks*2 + kh;
    // phys slot = chunk ^ ((row>>1)&3)
    int aoff[2][2], boff[2][2];
#pragma unroll
    for (int ks = 0; ks < 2; ks++) {
        const int slot = ((ks * 2 + kh) ^ ((mr >> 1) & 3)) * 16;
#pragma unroll
        for (int i = 0; i < 2; i++) aoff[i][ks] = (wm + i * 32 + mr) * 64 + slot;
#pragma unroll
        for (int j = 0; j < 2; j++) boff[j][ks] = (wn + j * 32 + mr) * 64 + slot;
    }

    auto stage = [&](int buf, int kt) {   // 4 global_load_lds per thread
        signed char* a_dst = As + buf * 8192 + tid * 16;
        signed char* b_dst = Bs + buf * 8192 + tid * 16;
#pragma unroll
        for (int p = 0; p < 2; p++)
            gload_lds16(A8 + arow + (size_t)p * 262144 + kt, a_dst + p * 4096);
#pragma unroll
        for (int p = 0; p < 2; p++)
            gload_lds16(B8T + brow + (size_t)p * 262144 + kt, b_dst + p * 4096);
    };
    auto compute = [&](int buf) {
        const signed char* Ab = As + buf * 8192;
        const signed char* Bb = Bs + buf * 8192;
#pragma unroll
        for (int ks = 0; ks < 2; ks++) {
            int32x4 af[2], bf[2];
#pragma unroll
            for (int i = 0; i < 2; i++) af[i] = *(const int32x4*)(Ab + aoff[i][ks]);
#pragma unroll
            for (int j = 0; j < 2; j++) bf[j] = *(const int32x4*)(Bb + boff[j][ks]);
#pragma unroll
            for (int i = 0; i < 2; i++)
#pragma unroll
                for (int j = 0; j < 2; j++)
                    acc[i][j] = MFMA_I8(af[i], bf[j], acc[i][j]);
        }
    };

    stage(0, 0);
    stage(1, 64);
    // waitcnt imm: vmcnt[3:0]=bits0-3, vmcnt[5:4]=bits14-15, exp=0x70, lgkm=0xF00
    // 0xF74 = vmcnt(4): tile i complete, newest 4 (tile i+1) in flight.
#pragma unroll 1
    for (int kt = 0; kt < 4096 - 64; kt += 64) {
        const int i = kt >> 6;
        __builtin_amdgcn_s_waitcnt(0xF74);   // tile i (2-old) landed
        __builtin_amdgcn_s_barrier();        // raw barrier: NO implicit drain
        __builtin_amdgcn_sched_barrier(0);   // keep ds_reads below the barrier
        if (kt + 128 < 4096) stage((i + 2) % 3, kt + 128);
        compute(i % 3);
    }
    __builtin_amdgcn_s_waitcnt(0xF70);       // vmcnt(0): last tile landed
    __builtin_amdgcn_s_barrier();
    __builtin_amdgcn_sched_barrier(0);
    compute(63 % 3);

    // Epilogue. C/D: col = lane&31, row = (reg&3) + 8*(reg>>2) + 4*kh
#pragma unroll
    for (int i = 0; i < 2; i++) {
#pragma unroll
        for (int r = 0; r < 16; r++) {
            const int gm = bm + wm + i * 32 + (r & 3) + 8 * (r >> 2) + 4 * kh;
            const int rcorr = -32 * rs[gm] - 8650752;
#pragma unroll
            for (int j = 0; j < 2; j++) {
                const int gn = bn + wn + j * 32 + mr;
                const int v = acc[i][j][r] + rcorr + 66 * sy[gn];
                C[(size_t)gm * 4096 + gn] = 7.5e-4f * (float)v;
            }
        }
    }
}

// ---------------------------------------------------------------------------
extern "C" void kernel_launch(void* const* d_in, const int* in_sizes, int n_in,
                              void* d_out, int out_size, void* d_ws, size_t ws_size,
                              hipStream_t stream) {
    const float* x = (const float*)d_in[0];  // [4096,4096] int8-valued
    const float* y = (const float*)d_in[1];  // [4096,4096] uint8-valued
    float* out = (float*)d_out;

    char* ws = (char*)d_ws;
    signed char* A8  = (signed char*)ws;                         // 16 MiB
    signed char* B8T = (signed char*)(ws + (16u << 20));         // 16 MiB
    int* rs = (int*)(ws + (32u << 20));                          // 16 KiB
    int* sy = (int*)(ws + (32u << 20) + (16u << 10));            // 16 KiB

    hipMemsetAsync(sy, 0, 4096 * sizeof(int), stream);
    quant_x<<<4096, 256, 0, stream>>>(x, A8, rs);
    quant_y<<<dim3(64, 64), 256, 0, stream>>>(y, B8T, sy);
    gemm_i8<<<dim3(32, 32), 256, 0, stream>>>(A8, B8T, rs, sy, out);
}

// Round 3
// 239.631 us; speedup vs baseline: 1.1424x; 1.1424x over previous
//
#include <hip/hip_runtime.h>
#include <cstdint>
#include <cstddef>

typedef int int32x4  __attribute__((ext_vector_type(4)));
typedef int int32x16 __attribute__((ext_vector_type(16)));

#define AS1 __attribute__((address_space(1)))
#define AS3 __attribute__((address_space(3)))

__device__ __forceinline__ void gload_lds16(const void* g, void* l) {
    __builtin_amdgcn_global_load_lds((const AS1 void*)g, (AS3 void*)l, 16, 0, 0);
}

#define MFMA_I8(a, b, c) __builtin_amdgcn_mfma_i32_32x32x32_i8((a), (b), (c), 0, 0, 0)

// ---------------------------------------------------------------------------
// Fused quant kernel: blocks [0,4096) do x-rows, [4096,8192) do y-tiles.
// Bodies identical to the proven round-1 kernels; fusion removes one launch
// gap and lets the two memory-bound phases co-fill the machine.
// ---------------------------------------------------------------------------
__global__ __launch_bounds__(256) void quant_xy(const float* __restrict__ x,
                                                const float* __restrict__ y,
                                                signed char* __restrict__ A8,
                                                signed char* __restrict__ B8T,
                                                int* __restrict__ rs,
                                                int* __restrict__ sy) {
    const int t = threadIdx.x;
    if (blockIdx.x < 4096) {
        // ---- x path: fp32 -> int8 + row sum ----
        const int row = blockIdx.x;
        const float4* xr = (const float4*)(x + (size_t)row * 4096);
        char4* ar = (char4*)(A8 + (size_t)row * 4096);
        int s = 0;
#pragma unroll
        for (int i = 0; i < 4; i++) {
            const int idx = i * 256 + t;
            float4 v = xr[idx];
            int a0 = (int)v.x, a1 = (int)v.y, a2 = (int)v.z, a3 = (int)v.w;
            s += a0 + a1 + a2 + a3;
            char4 c;
            c.x = (signed char)a0; c.y = (signed char)a1;
            c.z = (signed char)a2; c.w = (signed char)a3;
            ar[idx] = c;
        }
#pragma unroll
        for (int off = 32; off > 0; off >>= 1) s += __shfl_down(s, off);
        __shared__ int wsum[4];
        if ((t & 63) == 0) wsum[t >> 6] = s;
        __syncthreads();
        if (t == 0) rs[row] = wsum[0] + wsum[1] + wsum[2] + wsum[3];
    } else {
        // ---- y path: fp32 -> int8 (y-128), transposed to N-major + col sums ----
        const int q = blockIdx.x - 4096;
        __shared__ int tile[64 * 17];   // [n][k/4], pitch 17 dwords
        __shared__ int ssum[64];
        const int nt = (q & 63) * 64;
        const int kt = (q >> 6) * 64;
        if (t < 64) ssum[t] = 0;
        __syncthreads();

        const int n4 = (t & 15) * 4;
        const int kb = (t >> 4) * 4;
        int b[4][4];
#pragma unroll
        for (int i = 0; i < 4; i++) {
            float4 v = *(const float4*)(y + (size_t)(kt + kb + i) * 4096 + nt + n4);
            b[i][0] = (int)v.x - 128; b[i][1] = (int)v.y - 128;
            b[i][2] = (int)v.z - 128; b[i][3] = (int)v.w - 128;
        }
#pragma unroll
        for (int j = 0; j < 4; j++) {
            const int s = b[0][j] + b[1][j] + b[2][j] + b[3][j];
            const int w = (b[0][j] & 255) | ((b[1][j] & 255) << 8) |
                          ((b[2][j] & 255) << 16) | (b[3][j] << 24);
            tile[(n4 + j) * 17 + (kb >> 2)] = w;
            atomicAdd(&ssum[n4 + j], s);
        }
        __syncthreads();

        const int n = t >> 2;
        const int kq = (t & 3) * 4;
        int32x4 o;
        o.x = tile[n * 17 + kq + 0];
        o.y = tile[n * 17 + kq + 1];
        o.z = tile[n * 17 + kq + 2];
        o.w = tile[n * 17 + kq + 3];
        *(int32x4*)(B8T + (size_t)(nt + n) * 4096 + kt + kq * 4) = o;
        if (t < 64) atomicAdd(&sy[nt + t], ssum[t]);
    }
}

// ---------------------------------------------------------------------------
// Kernel 3: int8 GEMM — 256x256 8-wave phase-split template (T3+T4+T5).
// Evidence trail: r0/r1 = two schedules at 256x128/4w -> identical 88.5us,
// MfmaUtil 34% == the m97-structure ceiling (grafts null). r2 = 128x128
// occupancy attempt -> occupancy flat, FETCH 2x, 121us (refuted). The
// catalog's escape is the 256^2 8-wave phase template (62-69% bf16;
// regime gate: phase-split pays ONLY at 256^2 + 8 waves).
// Geometry: BM=BN=256, BK=64, 8 waves 2Mx4N, wave tile 128x64 = 4x2 of
// 32x32x32 i8 MFMA. LDS 3-stage ring x (16K+16K) = 96KB, 1 block/CU.
// Per K-tile: 2 phases (ks=0/1): {6 ds_read_b128 || 2 gload_lds -> BAR ->
// lgkmcnt(0) -> setprio(1) -> 8 MFMA -> setprio(0) -> BAR}. Counted
// vmcnt(4) only at iter top (tile i+1's 4 loads stay in flight across all
// barriers — never drained in the main loop).
// Safety: top vmcnt(4)+barrier => every wave's share of tile i is in LDS
// before any wave reads it. Gloads at iter i target buf (i+2)%3, whose
// previous readers (tile i-1) all passed iter i-1's trailing barrier.
// LDS layout: dense 64B rows, XOR chunk swizzle slot = chunk ^ ((row>>1)&3),
// applied on the GLOBAL source address (global_load_lds dest must be linear).
// Frags: A[m=lane&31][k=(lane>>5)*16+j]; C/D col=lane&31,
// row=(reg&3)+8*(reg>>2)+4*(lane>>5)  (verified rounds 0-2, absmax 32).
// XCD swizzle: 256 blocks, til=(lin&7)*32+(lin>>3), bijective (256%8==0);
// each XCD owns 2 consecutive M-rows of tiles.
// Epilogue: C = 7.5e-4 * (P - 32*rs[m] + 66*sy[n] - 8650752)
// ---------------------------------------------------------------------------
__global__ __launch_bounds__(512, 2) void gemm_i8(const signed char* __restrict__ A8,
                                                  const signed char* __restrict__ B8T,
                                                  const int* __restrict__ rs,
                                                  const int* __restrict__ sy,
                                                  float* __restrict__ C) {
    __shared__ __align__(16) signed char As[3 * 16384];  // 256 rows x 64B x 3
    __shared__ __align__(16) signed char Bs[3 * 16384];  // 256 rows x 64B x 3
    const int tid = threadIdx.x;
    const int lin = blockIdx.x;
    const int til = (lin & 7) * 32 + (lin >> 3);   // XCD-contiguous tiles
    const int bm = (til >> 4) * 256;
    const int bn = (til & 15) * 256;
    const int lane = tid & 63;
    const int wave = tid >> 6;
    const int wm = (wave >> 2) * 128;   // 2 m-waves x 128
    const int wn = (wave & 3) * 64;     // 4 n-waves x 64
    const int mr = lane & 31;
    const int kh = lane >> 5;

    int32x16 acc[4][2] = {};

    // staging: thread tid -> row (tid>>2) (+128*p), global chunk
    // (tid&3)^((tid>>3)&3) lands at phys slot tid&3 (XOR swizzle at source).
    // Works for p=1 too: row=128+q -> ((128+q)>>1)&3 == (q>>1)&3.
    const int srow = tid >> 2;
    const int scol = ((tid & 3) ^ ((tid >> 3) & 3)) * 16;
    const size_t arow = (size_t)(bm + srow) * 4096 + scol;
    const size_t brow = (size_t)(bn + srow) * 4096 + scol;

    // fragment LDS offsets: row = wtile + i*32 + mr (base multiple of 32 so
    // (row>>1)&3 == (mr>>1)&3); chunk = ks*2 + kh; slot = chunk ^ ((mr>>1)&3)
    int aoff[4][2], boff[2][2];
#pragma unroll
    for (int ks = 0; ks < 2; ks++) {
        const int slot = ((ks * 2 + kh) ^ ((mr >> 1) & 3)) * 16;
#pragma unroll
        for (int i = 0; i < 4; i++) aoff[i][ks] = (wm + i * 32 + mr) * 64 + slot;
#pragma unroll
        for (int j = 0; j < 2; j++) boff[j][ks] = (wn + j * 32 + mr) * 64 + slot;
    }

    auto stage = [&](int buf, int kt) {   // prologue: 4 gloads (2 A + 2 B)
        signed char* a_dst = As + buf * 16384 + tid * 16;
        signed char* b_dst = Bs + buf * 16384 + tid * 16;
#pragma unroll
        for (int p = 0; p < 2; p++)
            gload_lds16(A8 + arow + (size_t)p * 524288 + kt, a_dst + p * 8192);
#pragma unroll
        for (int p = 0; p < 2; p++)
            gload_lds16(B8T + brow + (size_t)p * 524288 + kt, b_dst + p * 8192);
    };
    auto compute = [&](int buf) {          // tail tile only
        const signed char* Ab = As + buf * 16384;
        const signed char* Bb = Bs + buf * 16384;
#pragma unroll
        for (int ks = 0; ks < 2; ks++) {
            int32x4 af[4], bf[2];
#pragma unroll
            for (int i = 0; i < 4; i++) af[i] = *(const int32x4*)(Ab + aoff[i][ks]);
#pragma unroll
            for (int j = 0; j < 2; j++) bf[j] = *(const int32x4*)(Bb + boff[j][ks]);
#pragma unroll
            for (int i = 0; i < 4; i++)
#pragma unroll
                for (int j = 0; j < 2; j++)
                    acc[i][j] = MFMA_I8(af[i], bf[j], acc[i][j]);
        }
    };

    stage(0, 0);
    stage(1, 64);
    // waitcnt imm: vmcnt[3:0]=bits0-3, vmcnt[5:4]=bits14-15, exp=0x70, lgkm=0xF00
    // 0xF74 = vmcnt(4) lgkm/exp don't-care. 0xC07F = lgkmcnt(0) vmcnt/exp
    // don't-care. 0xF70 = vmcnt(0).
#pragma unroll 1
    for (int kt = 0; kt < 4096 - 64; kt += 64) {
        const int i = kt >> 6;
        const signed char* Ab = As + (i % 3) * 16384;
        const signed char* Bb = Bs + (i % 3) * 16384;
        signed char* a_dst = As + ((i + 2) % 3) * 16384 + tid * 16;
        signed char* b_dst = Bs + ((i + 2) % 3) * 16384 + tid * 16;
        const size_t ga = arow + kt + 128;
        const size_t gb = brow + kt + 128;
        const bool st = (kt + 128 < 4096);

        __builtin_amdgcn_s_waitcnt(0xF74);   // own 4 loads of tile i landed
        __builtin_amdgcn_s_barrier();        // => ALL waves' tile-i data in LDS
        __builtin_amdgcn_sched_barrier(0);

        int32x4 af0, af1, af2, af3, bf0, bf1;
        // ================= phase 0 (ks=0) =================
        af0 = *(const int32x4*)(Ab + aoff[0][0]);
        af1 = *(const int32x4*)(Ab + aoff[1][0]);
        af2 = *(const int32x4*)(Ab + aoff[2][0]);
        af3 = *(const int32x4*)(Ab + aoff[3][0]);
        bf0 = *(const int32x4*)(Bb + boff[0][0]);
        bf1 = *(const int32x4*)(Bb + boff[1][0]);
        if (st) {   // stage A-halves of tile i+2
            gload_lds16(A8 + ga, a_dst);
            gload_lds16(A8 + ga + 524288, a_dst + 8192);
        }
        __builtin_amdgcn_sched_barrier(0);
        __builtin_amdgcn_s_barrier();
        __builtin_amdgcn_s_waitcnt(0xC07F);  // lgkmcnt(0)
        __builtin_amdgcn_sched_barrier(0);
        __builtin_amdgcn_s_setprio(1);
        acc[0][0] = MFMA_I8(af0, bf0, acc[0][0]);
        acc[0][1] = MFMA_I8(af0, bf1, acc[0][1]);
        acc[1][0] = MFMA_I8(af1, bf0, acc[1][0]);
        acc[1][1] = MFMA_I8(af1, bf1, acc[1][1]);
        acc[2][0] = MFMA_I8(af2, bf0, acc[2][0]);
        acc[2][1] = MFMA_I8(af2, bf1, acc[2][1]);
        acc[3][0] = MFMA_I8(af3, bf0, acc[3][0]);
        acc[3][1] = MFMA_I8(af3, bf1, acc[3][1]);
        __builtin_amdgcn_s_setprio(0);
        __builtin_amdgcn_s_barrier();
        __builtin_amdgcn_sched_barrier(0);
        // ================= phase 1 (ks=1) =================
        af0 = *(const int32x4*)(Ab + aoff[0][1]);
        af1 = *(const int32x4*)(Ab + aoff[1][1]);
        af2 = *(const int32x4*)(Ab + aoff[2][1]);
        af3 = *(const int32x4*)(Ab + aoff[3][1]);
        bf0 = *(const int32x4*)(Bb + boff[0][1]);
        bf1 = *(const int32x4*)(Bb + boff[1][1]);
        if (st) {   // stage B-halves of tile i+2
            gload_lds16(B8T + gb, b_dst);
            gload_lds16(B8T + gb + 524288, b_dst + 8192);
        }
        __builtin_amdgcn_sched_barrier(0);
        __builtin_amdgcn_s_barrier();
        __builtin_amdgcn_s_waitcnt(0xC07F);  // lgkmcnt(0)
        __builtin_amdgcn_sched_barrier(0);
        __builtin_amdgcn_s_setprio(1);
        acc[0][0] = MFMA_I8(af0, bf0, acc[0][0]);
        acc[0][1] = MFMA_I8(af0, bf1, acc[0][1]);
        acc[1][0] = MFMA_I8(af1, bf0, acc[1][0]);
        acc[1][1] = MFMA_I8(af1, bf1, acc[1][1]);
        acc[2][0] = MFMA_I8(af2, bf0, acc[2][0]);
        acc[2][1] = MFMA_I8(af2, bf1, acc[2][1]);
        acc[3][0] = MFMA_I8(af3, bf0, acc[3][0]);
        acc[3][1] = MFMA_I8(af3, bf1, acc[3][1]);
        __builtin_amdgcn_s_setprio(0);
        // no trailing barrier: next iter's vmcnt+barrier paces
    }
    __builtin_amdgcn_s_waitcnt(0xF70);       // vmcnt(0): last tile landed
    __builtin_amdgcn_s_barrier();
    __builtin_amdgcn_sched_barrier(0);
    compute(63 % 3);                         // == buf 0

    // Epilogue. C/D: col = lane&31, row = (reg&3) + 8*(reg>>2) + 4*kh
#pragma unroll
    for (int i = 0; i < 4; i++) {
#pragma unroll
        for (int r = 0; r < 16; r++) {
            const int gm = bm + wm + i * 32 + (r & 3) + 8 * (r >> 2) + 4 * kh;
            const int rcorr = -32 * rs[gm] - 8650752;
#pragma unroll
            for (int j = 0; j < 2; j++) {
                const int gn = bn + wn + j * 32 + mr;
                const int v = acc[i][j][r] + rcorr + 66 * sy[gn];
                C[(size_t)gm * 4096 + gn] = 7.5e-4f * (float)v;
            }
        }
    }
}

// ---------------------------------------------------------------------------
extern "C" void kernel_launch(void* const* d_in, const int* in_sizes, int n_in,
                              void* d_out, int out_size, void* d_ws, size_t ws_size,
                              hipStream_t stream) {
    const float* x = (const float*)d_in[0];  // [4096,4096] int8-valued
    const float* y = (const float*)d_in[1];  // [4096,4096] uint8-valued
    float* out = (float*)d_out;

    char* ws = (char*)d_ws;
    signed char* A8  = (signed char*)ws;                         // 16 MiB
    signed char* B8T = (signed char*)(ws + (16u << 20));         // 16 MiB
    int* rs = (int*)(ws + (32u << 20));                          // 16 KiB
    int* sy = (int*)(ws + (32u << 20) + (16u << 10));            // 16 KiB

    hipMemsetAsync(sy, 0, 4096 * sizeof(int), stream);
    quant_xy<<<8192, 256, 0, stream>>>(x, y, A8, B8T, rs, sy);
    gemm_i8<<<256, 512, 0, stream>>>(A8, B8T, rs, sy, out);
}